// Round 8
// baseline (116.251 us; speedup 1.0000x reference)
//
#include <hip/hip_runtime.h>

// SelfAttentionPool, fused single kernel v6b (round 8).
// Trajectory: R1 49us -> R4 31 -> R5 26us (v4 structure) -> R6 REGRESSED
// 30.4us (8-thread/row dot; reverted) -> R7 compile error (nontemporal
// builtin rejects HIP_vector_type; fixed here via native ext_vector alias).
// v6 = exact v4/R5 structure + micro-levers:
//  1. global loads (edges, theta, x) issued BEFORE LDS init + B1 -> HBM
//     latency hides behind init/barrier instead of being exposed.
//  2. zp zeroing moved to the dot/B2 slack slot (off the pre-B1 path).
//  3. nontemporal stores for all outputs (never re-read; skip L2 alloc).
// Numerics: bit-identical f64 z pipeline to passing R1-R6.
//
// Output (float32): x_new (80000*128) | edge0 (E) | edge1 (E) | batch_new (80000)

#define NPG   100
#define EPG   1600
#define KNUM  80
#define FDIM  128
#define BT    512
#define NF4   (NPG * FDIM / 4)   // 3200 float4 of x per graph
#define NE4   (EPG / 4)          // 400 int4 per edge row
#define NCH   (NF4 / BT)         // 6 full chunks, remainder 128

typedef float nfloat4 __attribute__((ext_vector_type(4)));   // native vec for NT builtins

__device__ __forceinline__ void nt_store4(float4* p, float4 v) {
    __builtin_nontemporal_store(__builtin_bit_cast(nfloat4, v),
                                reinterpret_cast<nfloat4*>(p));
}

__global__ __launch_bounds__(BT)
void sagpool_fused6(const float* __restrict__ x,
                    const int*   __restrict__ ei,
                    const float* __restrict__ theta,
                    float* __restrict__ out,
                    int E_total, int out_x_elems)
{
    const int g    = blockIdx.x;
    const int tid  = threadIdx.x;
    const int wave = tid >> 6;
    const int lane = tid & 63;
    const int base = g * NPG;

    __shared__ int4   sh_edge4[NE4];              // packed: s | (d<<16)
    __shared__ int    sh_deg[NPG];
    __shared__ double sh_s[NPG];
    __shared__ double sh_dis[NPG];
    __shared__ double sh_a[NPG];                  // s * dis
    __shared__ double sh_zp[8][NPG];              // per-wave private scatter
    __shared__ double sh_z[NPG];
    __shared__ unsigned long long sh_mask[2];
    __shared__ int    sh_newid[NPG];              // global out row, or -1
    __shared__ float  sh_scalen[NPG];             // sigmoid(z), by node
    int* sh_edge = (int*)sh_edge4;

    // ---- issue ALL global loads first: edges (waited on first), then the
    // x tile; LDS init + B1 then hide the HBM latency.
    const int4* src4 = (const int4*)(ei + (size_t)g * EPG);
    const int4* dst4 = (const int4*)(ei + (size_t)E_total + (size_t)g * EPG);
    const bool  hasE = tid < NE4;
    int4 es, ed;
    if (hasE) { es = src4[tid]; ed = dst4[tid]; }

    // theta fragment: fixed per lane (col4 = lane&31), registers only
    const float4 th = ((const float4*)theta)[lane & 31];

    const float4* xb4 = (const float4*)(x + (size_t)base * FDIM);
    float4 v[NCH];
    #pragma unroll
    for (int i = 0; i < NCH; ++i) v[i] = xb4[i * BT + tid];
    const bool hasR = tid < (NF4 - NCH * BT);     // last 128 float4
    float4 vR;
    if (hasR) vR = xb4[NCH * BT + tid];

    // ---- LDS init while loads are in flight
    if (tid < NPG) sh_deg[tid] = 1;               // self-loop
    __syncthreads();                              // B1: deg init visible

    // ---- edge pack + degree histogram (x loads still in flight)
    if (hasE) {
        int4 s4 = es, d4 = ed;
        s4.x -= base; s4.y -= base; s4.z -= base; s4.w -= base;
        d4.x -= base; d4.y -= base; d4.z -= base; d4.w -= base;
        int4 p; p.x = s4.x | (d4.x << 16); p.y = s4.y | (d4.y << 16);
                p.z = s4.z | (d4.z << 16); p.w = s4.w | (d4.w << 16);
        sh_edge4[tid] = p;
        atomicAdd(&sh_deg[s4.x], 1); atomicAdd(&sh_deg[s4.y], 1);
        atomicAdd(&sh_deg[s4.z], 1); atomicAdd(&sh_deg[s4.w], 1);
    }

    // ---- dot: f64 partial + 32-lane xor-tree (32 consecutive idx = 1 row)
    #pragma unroll
    for (int i = 0; i < NCH; ++i) {
        double p = (double)v[i].x * th.x + (double)v[i].y * th.y
                 + (double)v[i].z * th.z + (double)v[i].w * th.w;
        #pragma unroll
        for (int m = 1; m <= 16; m <<= 1) p += __shfl_xor(p, m, 64);
        if ((lane & 31) == 0) sh_s[(i * BT + tid) >> 5] = p;
    }
    if (hasR) {
        double p = (double)vR.x * th.x + (double)vR.y * th.y
                 + (double)vR.z * th.z + (double)vR.w * th.w;
        #pragma unroll
        for (int m = 1; m <= 16; m <<= 1) p += __shfl_xor(p, m, 64);
        if ((lane & 31) == 0) sh_s[(NCH * BT + tid) >> 5] = p;
    }

    // ---- zp zeroing in the dot->B2 slack (needed only after B3)
    for (int i = tid; i < 8 * NPG; i += BT) ((double*)sh_zp)[i] = 0.0;
    __syncthreads();                              // B2: edges, deg, s, zp ready

    if (tid < NPG) {
        double dis = 1.0 / sqrt((double)sh_deg[tid]);
        sh_dis[tid] = dis;
        sh_a[tid]   = sh_s[tid] * dis;
    }
    __syncthreads();                              // B3: dis/a ready

    // ---- z scatter into per-wave private arrays (f64 LDS atomics)
    {
        double* zp = sh_zp[wave];
        for (int j = tid; j < EPG; j += BT) {
            int p = sh_edge[j];
            int s = p & 0xffff;
            int d = p >> 16;
            atomicAdd(&zp[d], sh_a[s] * sh_dis[d]);
        }
    }
    __syncthreads();                              // B4: scatter done

    double zi = 0.0;
    if (tid < NPG) {
        zi = sh_a[tid] * sh_dis[tid]              // self-loop term
           + sh_zp[0][tid] + sh_zp[1][tid] + sh_zp[2][tid] + sh_zp[3][tid]
           + sh_zp[4][tid] + sh_zp[5][tid] + sh_zp[6][tid] + sh_zp[7][tid];
        sh_z[tid] = zi;
    }
    __syncthreads();                              // B5: z ready

    // ---- top-k by rank (tie-break: lower index wins)
    bool kept = false;
    if (tid < NPG) {
        int rank = 0;
        for (int j = 0; j < NPG; ++j) {
            double zj = sh_z[j];
            rank += (int)((zj > zi) | ((zj == zi) & (j < tid)));
        }
        kept = rank < KNUM;
        sh_newid[tid] = -1;
    }
    unsigned long long m = __ballot(kept);
    if (lane == 0 && wave < 2) sh_mask[wave] = m;
    __syncthreads();                              // masks + newid init

    if (kept) {
        int before = (wave == 0)
            ? __popcll(sh_mask[0] & ((1ull << lane) - 1ull))
            : __popcll(sh_mask[0]) + __popcll(sh_mask[1] & ((1ull << lane) - 1ull));
        int row = g * KNUM + before;
        sh_newid[tid]   = row;
        sh_scalen[tid]  = (float)(1.0 / (1.0 + exp(-zi)));
        float bg = (float)g;                      // batch_new, nontemporal
        __builtin_nontemporal_store(bg,
            out + (size_t)out_x_elems + 2 * (size_t)E_total + row);
    }
    __syncthreads();                              // B6: newid/scalen ready

    // ---- x_new straight from the register-resident tile (no re-read)
    float4* outx = (float4*)out;
    #pragma unroll
    for (int i = 0; i < NCH; ++i) {
        int idx = i * BT + tid;
        int row = idx >> 5;
        int nid = sh_newid[row];
        if (nid >= 0) {
            float sc = sh_scalen[row];
            float4 o;
            o.x = v[i].x * sc; o.y = v[i].y * sc;
            o.z = v[i].z * sc; o.w = v[i].w * sc;
            nt_store4(outx + (size_t)nid * 32 + (idx & 31), o);
        }
    }
    if (hasR) {
        int idx = NCH * BT + tid;
        int row = idx >> 5;
        int nid = sh_newid[row];
        if (nid >= 0) {
            float sc = sh_scalen[row];
            float4 o;
            o.x = vR.x * sc; o.y = vR.y * sc;
            o.z = vR.z * sc; o.w = vR.w * sc;
            nt_store4(outx + (size_t)nid * 32 + (idx & 31), o);
        }
    }

    // ---- edge relabel, nontemporal float4 stores
    float* e0 = out + out_x_elems;
    float* e1 = e0 + E_total;
    if (hasE) {
        int4 p = sh_edge4[tid];
        float4 o0, o1;
        {
            int s = p.x & 0xffff, d = p.x >> 16;
            int a = sh_newid[s], b = sh_newid[d];
            bool vv = (a >= 0) && (b >= 0);
            o0.x = vv ? (float)a : -1.0f; o1.x = vv ? (float)b : -1.0f;
        }
        {
            int s = p.y & 0xffff, d = p.y >> 16;
            int a = sh_newid[s], b = sh_newid[d];
            bool vv = (a >= 0) && (b >= 0);
            o0.y = vv ? (float)a : -1.0f; o1.y = vv ? (float)b : -1.0f;
        }
        {
            int s = p.z & 0xffff, d = p.z >> 16;
            int a = sh_newid[s], b = sh_newid[d];
            bool vv = (a >= 0) && (b >= 0);
            o0.z = vv ? (float)a : -1.0f; o1.z = vv ? (float)b : -1.0f;
        }
        {
            int s = p.w & 0xffff, d = p.w >> 16;
            int a = sh_newid[s], b = sh_newid[d];
            bool vv = (a >= 0) && (b >= 0);
            o0.w = vv ? (float)a : -1.0f; o1.w = vv ? (float)b : -1.0f;
        }
        nt_store4((float4*)e0 + (size_t)g * NE4 + tid, o0);
        nt_store4((float4*)e1 + (size_t)g * NE4 + tid, o1);
    }
}

extern "C" void kernel_launch(void* const* d_in, const int* in_sizes, int n_in,
                              void* d_out, int out_size, void* d_ws, size_t ws_size,
                              hipStream_t stream)
{
    const float* x     = (const float*)d_in[0];
    const int*   ei    = (const int*)d_in[1];
    const float* theta = (const float*)d_in[3];
    float* out = (float*)d_out;

    const int N = in_sizes[0] / FDIM;        // 100000
    const int E = in_sizes[1] / 2;           // 1600000
    const int B = N / NPG;                   // 1000
    const int out_x_elems = B * KNUM * FDIM; // 10,240,000

    sagpool_fused6<<<dim3(B), dim3(BT), 0, stream>>>(x, ei, theta, out, E, out_x_elems);
}